// Round 5
// baseline (965.529 us; speedup 1.0000x reference)
//
#include <hip/hip_runtime.h>
#include <cmath>

#define LSEQ   512
#define BATCH  128
#define EDIM   256
#define HDIM   128
#define GDIM   512      // 4*H2
#define NVOC   32001    // V+1 rows in emb table
#define PADROW 32000    // pad_id

typedef __attribute__((ext_vector_type(8))) _Float16 half8;
typedef __attribute__((ext_vector_type(4))) _Float16 half4;
typedef __attribute__((ext_vector_type(4))) float    f32x4;

#define LO_SCALE 4096.f
#define LO_INV   (1.f / 4096.f)

// ---------------------------------------------------------------------------
// Kernel 1: G[dir][v][n] = sum_e emb[v][e]*W_ih[n][e] + b[n], f32 out.
// hi/lo f16 split (3 MFMAs) => f32-equivalent accuracy.
// Tile 128(vocab) x 64(gates); grid.x = nb+8*dir so blocks sharing an A-tile
// are consecutive (L2/L3 reuse of emb).
// ---------------------------------------------------------------------------
__global__ __launch_bounds__(512) void g_gemm(
    const float* __restrict__ emb,
    const float* __restrict__ Wf, const float* __restrict__ Wb,
    const float* __restrict__ bf, const float* __restrict__ bb,
    float* __restrict__ G)
{
    const int nb  = blockIdx.x & 7;
    const int dir = blockIdx.x >> 3;
    const int mb  = blockIdx.y;   // 0..250
    const float* W    = dir ? Wb : Wf;
    const float* bias = dir ? bb : bf;
    float* Gd = G + (size_t)dir * NVOC * GDIM;

    __shared__ _Float16 Ah[128][136], Al[128][136];   // stride 272B (16B-aligned, 2-way free)
    __shared__ _Float16 Bh[64][136],  Bl[64][136];

    const int tid  = threadIdx.x;
    const int m0   = mb * 128;
    const int n0   = nb * 64;
    const int w    = tid >> 6;
    const int lane = tid & 63;
    const int lr   = lane & 15;
    const int lg   = lane >> 4;

    f32x4 acc_m[4], acc_x[4];
    #pragma unroll
    for (int nt = 0; nt < 4; ++nt) {
        acc_m[nt] = (f32x4){0.f, 0.f, 0.f, 0.f};
        acc_x[nt] = (f32x4){0.f, 0.f, 0.f, 0.f};
    }

    for (int kh = 0; kh < 2; ++kh) {
        __syncthreads();
        #pragma unroll
        for (int it = 0; it < 8; ++it) {          // A: 128 x 128
            int ch  = tid + 512 * it;
            int row = ch >> 5;
            int c4  = ch & 31;
            int v   = m0 + row; if (v > PADROW) v = PADROW;
            f32x4 s = *(const f32x4*)(emb + (size_t)v * EDIM + kh * 128 + c4 * 4);
            half4 hv, lv;
            #pragma unroll
            for (int j = 0; j < 4; ++j) {
                _Float16 hi = (_Float16)s[j];
                hv[j] = hi;
                lv[j] = (_Float16)((s[j] - (float)hi) * LO_SCALE);
            }
            *(half4*)&Ah[row][c4 * 4] = hv;
            *(half4*)&Al[row][c4 * 4] = lv;
        }
        #pragma unroll
        for (int it = 0; it < 4; ++it) {          // B: 64 x 128
            int ch  = tid + 512 * it;
            int row = ch >> 5;
            int c4  = ch & 31;
            f32x4 s = *(const f32x4*)(W + (size_t)(n0 + row) * EDIM + kh * 128 + c4 * 4);
            half4 hv, lv;
            #pragma unroll
            for (int j = 0; j < 4; ++j) {
                _Float16 hi = (_Float16)s[j];
                hv[j] = hi;
                lv[j] = (_Float16)((s[j] - (float)hi) * LO_SCALE);
            }
            *(half4*)&Bh[row][c4 * 4] = hv;
            *(half4*)&Bl[row][c4 * 4] = lv;
        }
        __syncthreads();

        #pragma unroll
        for (int ks = 0; ks < 4; ++ks) {
            half8 ah = *(const half8*)&Ah[16 * w + lr][32 * ks + 8 * lg];
            half8 al = *(const half8*)&Al[16 * w + lr][32 * ks + 8 * lg];
            #pragma unroll
            for (int nt = 0; nt < 4; ++nt) {
                half8 bh = *(const half8*)&Bh[16 * nt + lr][32 * ks + 8 * lg];
                half8 bl = *(const half8*)&Bl[16 * nt + lr][32 * ks + 8 * lg];
                acc_m[nt] = __builtin_amdgcn_mfma_f32_16x16x32_f16(ah, bh, acc_m[nt], 0, 0, 0);
                acc_x[nt] = __builtin_amdgcn_mfma_f32_16x16x32_f16(al, bh, acc_x[nt], 0, 0, 0);
                acc_x[nt] = __builtin_amdgcn_mfma_f32_16x16x32_f16(ah, bl, acc_x[nt], 0, 0, 0);
            }
        }
    }

    // C/D: col = lane&15 (n), row = (lane>>4)*4 + reg (m)
    #pragma unroll
    for (int nt = 0; nt < 4; ++nt) {
        int ng = n0 + nt * 16 + lr;
        float bv = bias[ng];
        #pragma unroll
        for (int r = 0; r < 4; ++r) {
            int v = m0 + 16 * w + 4 * lg + r;
            if (v < NVOC)
                Gd[(size_t)v * GDIM + ng] = acc_m[nt][r] + acc_x[nt][r] * LO_INV + bv;
        }
    }
}

// ---------------------------------------------------------------------------
// Kernel 2: LSTM scan, MFMA, 16 batch/block, gate-type-major wave tiling.
// Wave w owns n-tiles {128t + 16w + lr : t=0..3} => each lane holds ALL 4
// gates for its (m = 4*lg+r, j = 16*w+lr) pairs -> in-lane h-update,
// zero gates-LDS round trip, ONE barrier per step.
// W_hh as hi/lo f16 fragments in VGPRs (held all 512 steps).
// ---------------------------------------------------------------------------
__device__ __forceinline__ float sigm(float x) {
    return __builtin_amdgcn_rcpf(1.f + __builtin_amdgcn_exp2f(-1.4426950408889634f * x));
}
__device__ __forceinline__ float tanh_fast(float x) {
    return 1.f - 2.f * __builtin_amdgcn_rcpf(1.f + __builtin_amdgcn_exp2f(2.8853900817779268f * x));
}

__global__ __launch_bounds__(512) void lstm_scan_mfma(
    const int*   __restrict__ tokens,
    const float* __restrict__ Whh_f, const float* __restrict__ Whh_b,
    const float* __restrict__ G,
    float* __restrict__ out)
{
    const int dir = blockIdx.x >> 3;
    const int bg  = blockIdx.x & 7;          // batch group: b = 16*bg + m
    const float* Whh = dir ? Whh_b : Whh_f;
    const float* Gd  = G + (size_t)dir * NVOC * GDIM;

    __shared__ int      tok_sh[LSEQ][16];
    __shared__ _Float16 hh[2][16][HDIM + 8];   // stride 272B: 16B-aligned b128, 2-way free
    __shared__ _Float16 hl[2][16][HDIM + 8];

    const int tid  = threadIdx.x;
    const int w    = tid >> 6;
    const int lane = tid & 63;
    const int lr   = lane & 15;
    const int lg   = lane >> 4;

    for (int i = tid; i < LSEQ * 16; i += 512) {
        int l = i >> 4, m = i & 15;
        tok_sh[l][m] = tokens[(size_t)l * BATCH + 16 * bg + m];
    }
    for (int i = tid; i < 2 * 16 * (HDIM + 8); i += 512) {
        (&hh[0][0][0])[i] = (_Float16)0.f;
        (&hl[0][0][0])[i] = (_Float16)0.f;
    }

    // W_hh hi/lo B-fragments: n = 128*tt + 16*w + lr, k = 32*ks + 8*lg + j
    half8 wh[4][4], wl[4][4];
    #pragma unroll
    for (int tt = 0; tt < 4; ++tt) {
        int n = 128 * tt + 16 * w + lr;
        #pragma unroll
        for (int ks = 0; ks < 4; ++ks) {
            const float* wp = Whh + (size_t)n * HDIM + 32 * ks + 8 * lg;
            half8 hv, lv;
            #pragma unroll
            for (int j = 0; j < 8; ++j) {
                float x = wp[j];
                _Float16 hi = (_Float16)x;
                hv[j] = hi;
                lv[j] = (_Float16)((x - (float)hi) * LO_SCALE);
            }
            wh[tt][ks] = hv;
            wl[tt][ks] = lv;
        }
    }
    __syncthreads();

    const int jcol = 16 * w + lr;

    auto load_xg = [&](int tstep, float (&xg)[4][4]) {
        int l = dir ? (LSEQ - 1 - tstep) : tstep;
        #pragma unroll
        for (int r = 0; r < 4; ++r) {
            int tk = tok_sh[l][4 * lg + r];
            const float* p = Gd + (size_t)(tk < 0 ? PADROW : tk) * GDIM + jcol;
            #pragma unroll
            for (int tt = 0; tt < 4; ++tt)
                xg[tt][r] = p[128 * tt];          // xg[m=4lg+r][n=128tt+jcol]
        }
    };

    float cst[4] = {0.f, 0.f, 0.f, 0.f};
    float xgA[4][4], xgB[4][4];
    load_xg(0, xgA);

    auto step = [&](int t, float (&xgc)[4][4], float (&xgn)[4][4]) {
        const int cur = t & 1, nxt = cur ^ 1;
        const int l   = dir ? (LSEQ - 1 - t) : t;

        f32x4 am[4], ax[4];
        #pragma unroll
        for (int tt = 0; tt < 4; ++tt) {
            am[tt] = (f32x4){xgc[tt][0], xgc[tt][1], xgc[tt][2], xgc[tt][3]};
            ax[tt] = (f32x4){0.f, 0.f, 0.f, 0.f};
        }

        if (t + 1 < LSEQ) load_xg(t + 1, xgn);   // prefetch (in flight during MFMA)

        #pragma unroll
        for (int ks = 0; ks < 4; ++ks) {
            half8 ah = *(const half8*)&hh[cur][lr][32 * ks + 8 * lg];
            half8 al = *(const half8*)&hl[cur][lr][32 * ks + 8 * lg];
            #pragma unroll
            for (int tt = 0; tt < 4; ++tt) {
                am[tt] = __builtin_amdgcn_mfma_f32_16x16x32_f16(ah, wh[tt][ks], am[tt], 0, 0, 0);
                ax[tt] = __builtin_amdgcn_mfma_f32_16x16x32_f16(al, wh[tt][ks], ax[tt], 0, 0, 0);
                ax[tt] = __builtin_amdgcn_mfma_f32_16x16x32_f16(ah, wl[tt][ks], ax[tt], 0, 0, 0);
            }
        }

        const int4 tk4 = *(const int4*)&tok_sh[l][4 * lg];
        #pragma unroll
        for (int r = 0; r < 4; ++r) {
            float gi = am[0][r] + ax[0][r] * LO_INV;
            float gf = am[1][r] + ax[1][r] * LO_INV;
            float gg = am[2][r] + ax[2][r] * LO_INV;
            float go = am[3][r] + ax[3][r] * LO_INV;
            float iv = sigm(gi), fv = sigm(gf);
            float gv = tanh_fast(gg), ov = sigm(go);
            float cc = fv * cst[r] + iv * gv;
            float h  = ov * tanh_fast(cc);
            int tk = (r == 0) ? tk4.x : (r == 1) ? tk4.y : (r == 2) ? tk4.z : tk4.w;
            if (tk < 0) { cc = 0.f; h = 0.f; }
            cst[r] = cc;
            int m = 4 * lg + r;
            out[(size_t)l * (BATCH * 256) + (size_t)(16 * bg + m) * 256 + dir * HDIM + jcol] = h;
            _Float16 hhi = (_Float16)h;
            hh[nxt][m][jcol] = hhi;
            hl[nxt][m][jcol] = (_Float16)((h - (float)hhi) * LO_SCALE);
        }
        __syncthreads();
    };

    for (int t = 0; t < LSEQ; t += 2) {
        step(t,     xgA, xgB);
        step(t + 1, xgB, xgA);
    }
}

// ---------------------------------------------------------------------------
extern "C" void kernel_launch(void* const* d_in, const int* in_sizes, int n_in,
                              void* d_out, int out_size, void* d_ws, size_t ws_size,
                              hipStream_t stream) {
    const int*   tokens = (const int*)  d_in[0];
    // d_in[1] = mask (unused; token==-1 <=> mask==0)
    const float* emb    = (const float*)d_in[2];
    const float* W_ih_f = (const float*)d_in[3];
    const float* W_hh_f = (const float*)d_in[4];
    const float* b_f    = (const float*)d_in[5];
    const float* W_ih_b = (const float*)d_in[6];
    const float* W_hh_b = (const float*)d_in[7];
    const float* b_b    = (const float*)d_in[8];

    float* G = (float*)d_ws;   // [2][NVOC][512] f32 = 131 MB

    g_gemm<<<dim3(16, 251), 512, 0, stream>>>(emb, W_ih_f, W_ih_b, b_f, b_b, G);
    lstm_scan_mfma<<<16, 512, 0, stream>>>(tokens, W_hh_f, W_hh_b, G,
                                           (float*)d_out);
}

// Round 6
// 539.503 us; speedup vs baseline: 1.7897x; 1.7897x over previous
//
#include <hip/hip_runtime.h>
#include <cmath>

#define LSEQ   512
#define BATCH  128
#define EDIM   256
#define HDIM   128
#define GDIM   512      // 4*H2
#define NVOC   32001    // V+1 rows in emb table
#define PADROW 32000    // pad_id

typedef __attribute__((ext_vector_type(8))) _Float16 half8;
typedef __attribute__((ext_vector_type(4))) _Float16 half4;
typedef __attribute__((ext_vector_type(4))) float    f32x4;

#define LO_SCALE 4096.f
#define LO_INV   (1.f / 4096.f)

// ---------------------------------------------------------------------------
// Kernel 1: G[dir][v][n] = sum_e emb[v][e]*W_ih[n][e] + b[n], f32 out.
// hi/lo f16 split (3 MFMAs) => f32-equivalent accuracy. (passed round 5)
// ---------------------------------------------------------------------------
__global__ __launch_bounds__(512) void g_gemm(
    const float* __restrict__ emb,
    const float* __restrict__ Wf, const float* __restrict__ Wb,
    const float* __restrict__ bf, const float* __restrict__ bb,
    float* __restrict__ G)
{
    const int nb  = blockIdx.x & 7;
    const int dir = blockIdx.x >> 3;
    const int mb  = blockIdx.y;   // 0..250
    const float* W    = dir ? Wb : Wf;
    const float* bias = dir ? bb : bf;
    float* Gd = G + (size_t)dir * NVOC * GDIM;

    __shared__ _Float16 Ah[128][136], Al[128][136];
    __shared__ _Float16 Bh[64][136],  Bl[64][136];

    const int tid  = threadIdx.x;
    const int m0   = mb * 128;
    const int n0   = nb * 64;
    const int w    = tid >> 6;
    const int lane = tid & 63;
    const int lr   = lane & 15;
    const int lg   = lane >> 4;

    f32x4 acc_m[4], acc_x[4];
    #pragma unroll
    for (int nt = 0; nt < 4; ++nt) {
        acc_m[nt] = (f32x4){0.f, 0.f, 0.f, 0.f};
        acc_x[nt] = (f32x4){0.f, 0.f, 0.f, 0.f};
    }

    for (int kh = 0; kh < 2; ++kh) {
        __syncthreads();
        #pragma unroll
        for (int it = 0; it < 8; ++it) {          // A: 128 x 128
            int ch  = tid + 512 * it;
            int row = ch >> 5;
            int c4  = ch & 31;
            int v   = m0 + row; if (v > PADROW) v = PADROW;
            f32x4 s = *(const f32x4*)(emb + (size_t)v * EDIM + kh * 128 + c4 * 4);
            half4 hv, lv;
            #pragma unroll
            for (int jj = 0; jj < 4; ++jj) {
                _Float16 hi = (_Float16)s[jj];
                hv[jj] = hi;
                lv[jj] = (_Float16)((s[jj] - (float)hi) * LO_SCALE);
            }
            *(half4*)&Ah[row][c4 * 4] = hv;
            *(half4*)&Al[row][c4 * 4] = lv;
        }
        #pragma unroll
        for (int it = 0; it < 4; ++it) {          // B: 64 x 128
            int ch  = tid + 512 * it;
            int row = ch >> 5;
            int c4  = ch & 31;
            f32x4 s = *(const f32x4*)(W + (size_t)(n0 + row) * EDIM + kh * 128 + c4 * 4);
            half4 hv, lv;
            #pragma unroll
            for (int jj = 0; jj < 4; ++jj) {
                _Float16 hi = (_Float16)s[jj];
                hv[jj] = hi;
                lv[jj] = (_Float16)((s[jj] - (float)hi) * LO_SCALE);
            }
            *(half4*)&Bh[row][c4 * 4] = hv;
            *(half4*)&Bl[row][c4 * 4] = lv;
        }
        __syncthreads();

        #pragma unroll
        for (int ks = 0; ks < 4; ++ks) {
            half8 ah = *(const half8*)&Ah[16 * w + lr][32 * ks + 8 * lg];
            half8 al = *(const half8*)&Al[16 * w + lr][32 * ks + 8 * lg];
            #pragma unroll
            for (int nt = 0; nt < 4; ++nt) {
                half8 bh = *(const half8*)&Bh[16 * nt + lr][32 * ks + 8 * lg];
                half8 bl = *(const half8*)&Bl[16 * nt + lr][32 * ks + 8 * lg];
                acc_m[nt] = __builtin_amdgcn_mfma_f32_16x16x32_f16(ah, bh, acc_m[nt], 0, 0, 0);
                acc_x[nt] = __builtin_amdgcn_mfma_f32_16x16x32_f16(al, bh, acc_x[nt], 0, 0, 0);
                acc_x[nt] = __builtin_amdgcn_mfma_f32_16x16x32_f16(ah, bl, acc_x[nt], 0, 0, 0);
            }
        }
    }

    // C/D: col = lane&15 (n), row = (lane>>4)*4 + reg (m)
    #pragma unroll
    for (int nt = 0; nt < 4; ++nt) {
        int ng = n0 + nt * 16 + lr;
        float bv = bias[ng];
        #pragma unroll
        for (int r = 0; r < 4; ++r) {
            int v = m0 + 16 * w + 4 * lg + r;
            if (v < NVOC)
                Gd[(size_t)v * GDIM + ng] = acc_m[nt][r] + acc_x[nt][r] * LO_INV + bv;
        }
    }
}

// ---------------------------------------------------------------------------
// Kernel 2: LSTM scan v2. 256 blocks (1 sequence each) x 512 threads.
// Thread (w, lr, lg): column j = 16w+lr, k-slice [32lg, 32lg+32).
// Computes all 4 gates for j over its k-quarter (128 FMA), butterfly-reduces
// across lg via shfl_xor(16,32) -> gates in-register, ONE barrier/step.
// W_hh in 128 VGPRs (chunk-rotated so all register indices are literal).
// ---------------------------------------------------------------------------
__device__ __forceinline__ float sigm(float x) {
    return __builtin_amdgcn_rcpf(1.f + __builtin_amdgcn_exp2f(-1.4426950408889634f * x));
}
__device__ __forceinline__ float tanh_fast(float x) {
    return 1.f - 2.f * __builtin_amdgcn_rcpf(1.f + __builtin_amdgcn_exp2f(2.8853900817779268f * x));
}

__global__ __launch_bounds__(512) void lstm_scan_v2(
    const int*   __restrict__ tokens,
    const float* __restrict__ Whh_f, const float* __restrict__ Whh_b,
    const float* __restrict__ G,
    float* __restrict__ out)
{
    const int dir = blockIdx.x >> 7;
    const int b   = blockIdx.x & 127;
    const float* Whh = dir ? Whh_b : Whh_f;
    const float* Gd  = G + (size_t)dir * NVOC * GDIM;

    __shared__ int   tok[LSEQ];
    __shared__ float hbuf[2][HDIM];

    const int tid  = threadIdx.x;
    const int w    = tid >> 6;
    const int lane = tid & 63;
    const int lr   = lane & 15;
    const int lg   = lane >> 4;
    const int j    = 16 * w + lr;

    tok[tid] = tokens[(size_t)tid * BATCH + b];
    if (tid < 2 * HDIM) ((float*)hbuf)[tid] = 0.f;

    // W_hh fragments, chunk-rotated: slot i <-> k-chunk c=(i+2lg)&7 of this
    // lane's k-quarter. Rotation makes the 4 lg-streams bank-disjoint per read.
    float wreg[4][8][4];
    int   offs[8];
    #pragma unroll
    for (int i = 0; i < 8; ++i) {
        int c   = (i + 2 * lg) & 7;
        offs[i] = 128 * lg + 16 * c;              // byte offset into h row
        #pragma unroll
        for (int gt = 0; gt < 4; ++gt) {
            f32x4 v = *(const f32x4*)(Whh + (size_t)(128 * gt + j) * HDIM + 32 * lg + 4 * c);
            wreg[gt][i][0] = v.x; wreg[gt][i][1] = v.y;
            wreg[gt][i][2] = v.z; wreg[gt][i][3] = v.w;
        }
    }
    __syncthreads();

    auto rowof = [&](int t) -> int {
        int l  = dir ? (LSEQ - 1 - t) : t;
        int tk = tok[l];
        return (tk < 0) ? PADROW : tk;
    };

    float xgA[4], xgB[4];
    {
        size_t ro = (size_t)rowof(0) * GDIM;
        #pragma unroll
        for (int gt = 0; gt < 4; ++gt) xgA[gt] = Gd[ro + 128 * gt + j];
    }

    float c = 0.f;
    const size_t out_base = (size_t)b * 256 + (size_t)dir * HDIM + j;

    auto step = [&](int t, float (&xgc)[4], float (&xgn)[4]) {
        const int l = dir ? (LSEQ - 1 - t) : t;

        // prefetch next step's xg (left in flight across the barrier)
        if (t + 1 < LSEQ) {
            size_t ro = (size_t)rowof(t + 1) * GDIM;
            #pragma unroll
            for (int gt = 0; gt < 4; ++gt) xgn[gt] = Gd[ro + 128 * gt + j];
        }

        // h k-quarter, rotated chunks (bank-disjoint across lg, broadcast over lr)
        const char* hB = (const char*)&hbuf[t & 1][0];
        f32x4 hc[8];
        #pragma unroll
        for (int i = 0; i < 8; ++i) hc[i] = *(const f32x4*)(hB + offs[i]);

        float a0 = 0.f, a1 = 0.f, a2 = 0.f, a3 = 0.f;
        #pragma unroll
        for (int i = 0; i < 8; ++i) {
            #pragma unroll
            for (int m = 0; m < 4; ++m) {
                a0 = fmaf(hc[i][m], wreg[0][i][m], a0);
                a1 = fmaf(hc[i][m], wreg[1][i][m], a1);
                a2 = fmaf(hc[i][m], wreg[2][i][m], a2);
                a3 = fmaf(hc[i][m], wreg[3][i][m], a3);
            }
        }
        // butterfly reduce across lg (lanes ^16, ^32): all lanes get full sums
        a0 += __shfl_xor(a0, 16); a0 += __shfl_xor(a0, 32);
        a1 += __shfl_xor(a1, 16); a1 += __shfl_xor(a1, 32);
        a2 += __shfl_xor(a2, 16); a2 += __shfl_xor(a2, 32);
        a3 += __shfl_xor(a3, 16); a3 += __shfl_xor(a3, 32);

        float iv = sigm(a0 + xgc[0]);
        float fv = sigm(a1 + xgc[1]);
        float gv = tanh_fast(a2 + xgc[2]);
        float ov = sigm(a3 + xgc[3]);
        c = fv * c + iv * gv;
        float h = ov * tanh_fast(c);
        if (tok[l] < 0) { c = 0.f; h = 0.f; }   // wave-uniform branch

        if (lg == 0) {
            hbuf[(t + 1) & 1][j] = h;
            out[(size_t)l * (BATCH * 256) + out_base] = h;
        }
        // LDS visibility only; keep global prefetch (vmcnt) in flight
        asm volatile("s_waitcnt lgkmcnt(0)" ::: "memory");
        __builtin_amdgcn_s_barrier();
    };

    for (int t = 0; t < LSEQ; t += 2) {
        step(t,     xgA, xgB);
        step(t + 1, xgB, xgA);
    }
}

// ---------------------------------------------------------------------------
extern "C" void kernel_launch(void* const* d_in, const int* in_sizes, int n_in,
                              void* d_out, int out_size, void* d_ws, size_t ws_size,
                              hipStream_t stream) {
    const int*   tokens = (const int*)  d_in[0];
    // d_in[1] = mask (unused; token==-1 <=> mask==0)
    const float* emb    = (const float*)d_in[2];
    const float* W_ih_f = (const float*)d_in[3];
    const float* W_hh_f = (const float*)d_in[4];
    const float* b_f    = (const float*)d_in[5];
    const float* W_ih_b = (const float*)d_in[6];
    const float* W_hh_b = (const float*)d_in[7];
    const float* b_b    = (const float*)d_in[8];

    float* G = (float*)d_ws;   // [2][NVOC][512] f32 = 131 MB

    g_gemm<<<dim3(16, 251), 512, 0, stream>>>(emb, W_ih_f, W_ih_b, b_f, b_b, G);
    lstm_scan_v2<<<256, 512, 0, stream>>>(tokens, W_hh_f, W_hh_b, G,
                                          (float*)d_out);
}